// Round 7
// baseline (22.823 us; speedup 1.0000x reference)
//
#include <hip/hip_runtime.h>

// Sparsemax over last axis. B=8, N=4096, D=512, fp32 in/out.
// R6 base: one 64-lane wave per row, 8 vals/lane, 32768 waves.
// Butterfly reductions: DPP (xor1/2/4/8, VALU) + __shfl_xor(16) +
// permlane32_swap (xor32 on the VALU pipe, replacing ds_swizzle).
// tau0 = rowmax - 1; Michelot fixed-point (monotone from below: the max
// element contributes >= its weight each step, support strictly shrinks).
// tau update via v_rcp_f32 (1 ulp; threshold 2e-2). Non-temporal stores.

constexpr int D   = 512;
constexpr int NW  = 64;
constexpr int VPT = D / NW;    // 8 values per lane

typedef float    f32x4 __attribute__((ext_vector_type(4)));
typedef unsigned u32x2 __attribute__((ext_vector_type(2)));

template <int CTRL>
__device__ __forceinline__ float dpp_mov_f32(float x) {
    return __builtin_bit_cast(float,
        __builtin_amdgcn_update_dpp(0, __builtin_bit_cast(int, x),
                                    CTRL, 0xF, 0xF, true));
}

// value held by lane^32, via v_permlane32_swap_b32 (VALU pipe).
// swap(a,b): a'[32:63] = b[0:31], b'[0:31] = a[32:63]. With a=b=x:
//   ret0 = [x_lo | x_lo], ret1 = [x_hi | x_hi]
// lane<32 wants x_hi -> ret1;  lane>=32 wants x_lo -> ret0.
__device__ __forceinline__ float xor32_f32(float x, bool lo_half) {
    u32x2 pr = __builtin_amdgcn_permlane32_swap(
        __builtin_bit_cast(unsigned, x), __builtin_bit_cast(unsigned, x),
        false, false);
    return __builtin_bit_cast(float, lo_half ? pr[1] : pr[0]);
}

__device__ __forceinline__ float wave_sum(float x, bool lo_half) {
    x += dpp_mov_f32<0xB1>(x);    // xor1: quad_perm(1,0,3,2)
    x += dpp_mov_f32<0x4E>(x);    // xor2: quad_perm(2,3,0,1)
    x += dpp_mov_f32<0x141>(x);   // xor4: row_half_mirror
    x += dpp_mov_f32<0x140>(x);   // xor8: row_mirror
    x += __shfl_xor(x, 16, NW);   // xor16
    x += xor32_f32(x, lo_half);   // xor32 via permlane32_swap
    return x;
}

__device__ __forceinline__ float wave_max(float x, bool lo_half) {
    x = fmaxf(x, dpp_mov_f32<0xB1>(x));
    x = fmaxf(x, dpp_mov_f32<0x4E>(x));
    x = fmaxf(x, dpp_mov_f32<0x141>(x));
    x = fmaxf(x, dpp_mov_f32<0x140>(x));
    x = fmaxf(x, __shfl_xor(x, 16, NW));
    x = fmaxf(x, xor32_f32(x, lo_half));
    return x;
}

__global__ __launch_bounds__(256)
void sparsemax_kernel(const float* __restrict__ in, float* __restrict__ out,
                      int nrows) {
    const int  lane    = threadIdx.x & (NW - 1);
    const bool lo_half = lane < 32;
    const int  wave    = threadIdx.x >> 6;
    const int  row     = blockIdx.x * 4 + wave;
    if (row >= nrows) return;

    const f32x4* rp = reinterpret_cast<const f32x4*>(in + (size_t)row * D);
    f32x4*       op = reinterpret_cast<f32x4*>(out + (size_t)row * D);

    const f32x4 a = rp[lane];
    const f32x4 b = rp[NW + lane];
    float v[VPT] = {a.x, a.y, a.z, a.w, b.x, b.y, b.z, b.w};

    // ---- wave max ----
    float m = v[0];
#pragma unroll
    for (int i = 1; i < VPT; ++i) m = fmaxf(m, v[i]);
    m = wave_max(m, lo_half);

    // ---- Michelot fixed-point from tau0 = max - 1 ----
    float tau  = m - 1.0f;
    int   prev = 1 << 30;
    for (int it = 0; it < D; ++it) {
        float ps = 0.f;
        int   pc = 0;
#pragma unroll
        for (int i = 0; i < VPT; ++i) {
            const bool g = v[i] > tau;
            ps += g ? v[i] : 0.0f;
            pc += (int)__popcll(__ballot(g));   // reuses v_cmp; s_bcnt1_b64
        }
        ps = wave_sum(ps, lo_half);
        tau = (ps - 1.0f) * __builtin_amdgcn_rcpf((float)pc);  // pc >= 1
        if (pc >= prev) break;                  // support stopped shrinking
        prev = pc;
    }

    // ---- output: relu(z - tau), non-temporal float4 stores ----
    f32x4 o0, o1;
    o0.x = fmaxf(v[0] - tau, 0.0f);  o0.y = fmaxf(v[1] - tau, 0.0f);
    o0.z = fmaxf(v[2] - tau, 0.0f);  o0.w = fmaxf(v[3] - tau, 0.0f);
    o1.x = fmaxf(v[4] - tau, 0.0f);  o1.y = fmaxf(v[5] - tau, 0.0f);
    o1.z = fmaxf(v[6] - tau, 0.0f);  o1.w = fmaxf(v[7] - tau, 0.0f);
    __builtin_nontemporal_store(o0, op + lane);
    __builtin_nontemporal_store(o1, op + NW + lane);
}

extern "C" void kernel_launch(void* const* d_in, const int* in_sizes, int n_in,
                              void* d_out, int out_size, void* d_ws, size_t ws_size,
                              hipStream_t stream) {
    const float* in  = (const float*)d_in[0];   // inputs [B,N,D]; mask unused
    float*       out = (float*)d_out;
    const int nrows = out_size / D;             // 32768

    const int grid = (nrows + 3) / 4;           // 4 waves/block, 1 row/wave
    sparsemax_kernel<<<grid, 256, 0, stream>>>(in, out, nrows);
}